// Round 1
// 146.854 us; speedup vs baseline: 1.0470x; 1.0470x over previous
//
#include <hip/hip_runtime.h>
#include <hip/hip_bf16.h>

using bf16 = __hip_bfloat16;
typedef __bf16 bf16x8 __attribute__((ext_vector_type(8)));
typedef float floatx4 __attribute__((ext_vector_type(4)));

// Problem dims
constexpr int BB = 4, SS = 2048, DIN = 512, DKK = 2048, DVV = 64;
constexpr int ROWS = BB * SS;          // 8192
constexpr int LDY = 640;               // yv row: y(512) | pad(128, garbage ok)

// ---- workspace layout (bytes) ----
// scores = x·(Wq Wk^T)·x^T: Mt[j][i] = sum_n Wk[j,n]Wq[i,n]; y = xb·Mt^T; scores = y·xb^T (K=512)
constexpr size_t XB_OFF  = 0;                          // bf16 xb  [8192][512]   (8 MB, live to the end)
constexpr size_t WQB_OFF = XB_OFF  + 8388608;          // bf16 wqb [512][2048]   (2 MB)
constexpr size_t WKB_OFF = WQB_OFF + 2097152;          // bf16 wkb [512][2048]   (2 MB)
constexpr size_t WT2_OFF = WKB_OFF + 2097152;          // bf16 wt2 [640][512]: rows 0..511 Mt, 512..575 Wv^T, 576..639 garbage
constexpr size_t MTP_OFF = WT2_OFF + 655360;           // fp32 mt partials [8][512][512] (8 MB)
constexpr size_t YV_OFF  = MTP_OFF + 8388608;          // bf16 yv  [8192][640]   (10 MB)
constexpr size_t VT_OFF  = YV_OFF  + 10485760;         // bf16 vt  [4][64][2048] (1 MB)
constexpr size_t PRT_OFF = VT_OFF  + 1048576;          // bf16 O' partials [4][16][2048][64] (16 MB)
constexpr size_t STA_OFF = PRT_OFF + 16777216;         // fp32 stats [4][16][2048][2] (1 MB)

__device__ __forceinline__ void async_copy16(const bf16* g, const unsigned short* l) {
    __builtin_amdgcn_global_load_lds((const __attribute__((address_space(1))) void*)g,
                                     (__attribute__((address_space(3))) void*)l, 16, 0, 0);
}

// ---------------- fused prep: convert x | convert Wq,Wk | transpose Wv ----------------
// blocks [0,4096): x -> xb (bf16, float4-vectorized)
// blocks [4096,6144): Wq|Wk -> wqb|wkb
// blocks [6144,6176): Wv [512][64] -> wt2 rows 512..575 as [64][512] (LDS-tiled)
__global__ __launch_bounds__(256) void prep(const float* __restrict__ x,
                                            const float* __restrict__ Wq,
                                            const float* __restrict__ Wk,
                                            const float* __restrict__ Wv,
                                            bf16* __restrict__ xb,
                                            bf16* __restrict__ wqb,
                                            bf16* __restrict__ wkb,
                                            bf16* __restrict__ wt2) {
    __shared__ float tile[32][33];
    const int bid = blockIdx.x;
    const int tid = threadIdx.x;

    if (bid < 4096) {
        int i = bid * 256 + tid;                     // over 1048576 float4 groups
        float4 v = reinterpret_cast<const float4*>(x)[i];
        union { bf16 h[4]; ushort4 u; } cv;
        cv.h[0] = __float2bfloat16(v.x);
        cv.h[1] = __float2bfloat16(v.y);
        cv.h[2] = __float2bfloat16(v.z);
        cv.h[3] = __float2bfloat16(v.w);
        reinterpret_cast<ushort4*>(xb)[i] = cv.u;
    } else if (bid < 6144) {
        int i = (bid - 4096) * 256 + tid;            // over 524288 float4 groups
        const float* src = (i < 262144) ? Wq : Wk;
        bf16* dst = (i < 262144) ? wqb : wkb;
        int j = (i < 262144) ? i : i - 262144;
        float4 v = reinterpret_cast<const float4*>(src)[j];
        union { bf16 h[4]; ushort4 u; } cv;
        cv.h[0] = __float2bfloat16(v.x);
        cv.h[1] = __float2bfloat16(v.y);
        cv.h[2] = __float2bfloat16(v.z);
        cv.h[3] = __float2bfloat16(v.w);
        reinterpret_cast<ushort4*>(dst)[j] = cv.u;
    } else {
        int idx = bid - 6144;                        // 0..31
        int n0 = (idx & 1) * 32;
        int k0 = (idx >> 1) * 32;
        int nn = tid & 31, kk8 = tid >> 5;
        #pragma unroll
        for (int p = 0; p < 4; ++p) {
            int k = p * 8 + kk8;
            tile[k][nn] = Wv[(long long)(k0 + k) * 64 + n0 + nn];
        }
        __syncthreads();
        int kk = tid & 31, nn8 = tid >> 5;
        #pragma unroll
        for (int p = 0; p < 4; ++p) {
            int n = p * 8 + nn8;
            wt2[(long long)(512 + n0 + n) * 512 + k0 + kk] = __float2bfloat16(tile[kk][n]);
        }
    }
}

// ---------------- Mt partial GEMM: Mt[j][i] = sum_n wkb[j][n]*wqb[i][n], split-K 8 ----------------
__global__ __launch_bounds__(256) void gemm_mt(const bf16* __restrict__ A,
                                               const bf16* __restrict__ Bt,
                                               float* __restrict__ Cp) {
    __shared__ __align__(16) unsigned short As[128 * 64];
    __shared__ __align__(16) unsigned short Bs[128 * 64];

    const int tid = threadIdx.x;
    const int lane = tid & 63, wave = tid >> 6;
    const long long m0 = (long long)blockIdx.y * 128;
    const long long n0 = (long long)blockIdx.x * 128;
    const int koff = blockIdx.z * 256;

    const int rIn = lane >> 3;
    const int cSwz = ((lane & 7) ^ rIn) * 8;
    const int wm0 = (wave >> 1) * 64, wn0 = (wave & 1) * 64;
    const int l15 = lane & 15, quad = lane >> 4;
    const int sw7 = l15 & 7;

    floatx4 acc[4][4] = {};

    for (int k0 = koff; k0 < koff + 256; k0 += 64) {
        #pragma unroll
        for (int t0 = 0; t0 < 8; ++t0) {
            int t = t0 * 4 + wave;
            if (t < 16)
                async_copy16(A + (m0 + t * 8 + rIn) * 2048LL + k0 + cSwz, &As[t * 512]);
            else
                async_copy16(Bt + (n0 + (t - 16) * 8 + rIn) * 2048LL + k0 + cSwz, &Bs[(t - 16) * 512]);
        }
        __syncthreads();
        #pragma unroll
        for (int sk = 0; sk < 2; ++sk) {
            const int rchunk = (((sk << 2) | quad) ^ sw7) * 8;
            bf16x8 af[4], bfr[4];
            #pragma unroll
            for (int mi = 0; mi < 4; ++mi)
                af[mi] = *reinterpret_cast<const bf16x8*>(&As[(wm0 + mi * 16 + l15) * 64 + rchunk]);
            #pragma unroll
            for (int ni = 0; ni < 4; ++ni)
                bfr[ni] = *reinterpret_cast<const bf16x8*>(&Bs[(wn0 + ni * 16 + l15) * 64 + rchunk]);
            #pragma unroll
            for (int mi = 0; mi < 4; ++mi)
                #pragma unroll
                for (int ni = 0; ni < 4; ++ni)
                    acc[mi][ni] = __builtin_amdgcn_mfma_f32_16x16x32_bf16(af[mi], bfr[ni],
                                                                          acc[mi][ni], 0, 0, 0);
        }
        __syncthreads();
    }

    float* C = Cp + (long long)blockIdx.z * 262144;
    #pragma unroll
    for (int mi = 0; mi < 4; ++mi) {
        long long row0 = m0 + wm0 + mi * 16 + quad * 4;
        #pragma unroll
        for (int ni = 0; ni < 4; ++ni) {
            long long col = n0 + wn0 + ni * 16 + l15;
            #pragma unroll
            for (int r = 0; r < 4; ++r)
                C[(row0 + r) * 512 + col] = acc[mi][ni][r];
        }
    }
}

// ---------------- reduce Mt partials -> wt2 rows 0..511 (bf16) ----------------
__global__ __launch_bounds__(256) void reduce_mt(const float4* __restrict__ part,
                                                 bf16* __restrict__ wt2) {
    int i = blockIdx.x * 256 + threadIdx.x;          // over 65536 float4 groups
    float4 s = {0.f, 0.f, 0.f, 0.f};
    #pragma unroll
    for (int t = 0; t < 8; ++t) {
        float4 a = part[(long long)t * 65536 + i];
        s.x += a.x; s.y += a.y; s.z += a.z; s.w += a.w;
    }
    union { bf16 h[4]; ushort4 u; } cv;
    cv.h[0] = __float2bfloat16(s.x);
    cv.h[1] = __float2bfloat16(s.y);
    cv.h[2] = __float2bfloat16(s.z);
    cv.h[3] = __float2bfloat16(s.w);
    reinterpret_cast<ushort4*>(wt2)[i] = cv.u;
}

// ---------------- yv GEMM: yv[8192][0..512) = xb . wt2^T, K=512 ----------------
// N-tiles 0..3 produce y = x·M into yv. N-tile 4 produces v = x·Wv and writes it
// TRANSPOSED directly to vt (fusing the old transpose_v kernel); its yv columns
// are dead and not stored.
__global__ __launch_bounds__(256) void gemm_proj(const bf16* __restrict__ A,
                                                 const bf16* __restrict__ Bt,
                                                 bf16* __restrict__ C,
                                                 bf16* __restrict__ vt) {
    __shared__ __align__(16) unsigned short As[128 * 64];
    __shared__ __align__(16) unsigned short Bs[128 * 64];

    const int tid = threadIdx.x;
    const int lane = tid & 63, wave = tid >> 6;
    const long long m0 = (long long)blockIdx.y * 128;
    const long long n0 = (long long)blockIdx.x * 128;

    const int rIn = lane >> 3;
    const int cSwz = ((lane & 7) ^ rIn) * 8;
    const int wm0 = (wave >> 1) * 64, wn0 = (wave & 1) * 64;
    const int l15 = lane & 15, quad = lane >> 4;
    const int sw7 = l15 & 7;

    floatx4 acc[4][4] = {};

    for (int k0 = 0; k0 < DIN; k0 += 64) {
        #pragma unroll
        for (int t0 = 0; t0 < 8; ++t0) {
            int t = t0 * 4 + wave;
            if (t < 16)
                async_copy16(A + (m0 + t * 8 + rIn) * (long long)DIN + k0 + cSwz, &As[t * 512]);
            else
                async_copy16(Bt + (n0 + (t - 16) * 8 + rIn) * (long long)DIN + k0 + cSwz, &Bs[(t - 16) * 512]);
        }
        __syncthreads();
        #pragma unroll
        for (int sk = 0; sk < 2; ++sk) {
            const int rchunk = (((sk << 2) | quad) ^ sw7) * 8;
            bf16x8 af[4], bfr[4];
            #pragma unroll
            for (int mi = 0; mi < 4; ++mi)
                af[mi] = *reinterpret_cast<const bf16x8*>(&As[(wm0 + mi * 16 + l15) * 64 + rchunk]);
            #pragma unroll
            for (int ni = 0; ni < 4; ++ni)
                bfr[ni] = *reinterpret_cast<const bf16x8*>(&Bs[(wn0 + ni * 16 + l15) * 64 + rchunk]);
            #pragma unroll
            for (int mi = 0; mi < 4; ++mi)
                #pragma unroll
                for (int ni = 0; ni < 4; ++ni)
                    acc[mi][ni] = __builtin_amdgcn_mfma_f32_16x16x32_bf16(af[mi], bfr[ni],
                                                                          acc[mi][ni], 0, 0, 0);
        }
        __syncthreads();
    }

    if (n0 < 512) {
        // y columns -> yv (row stride LDY)
        #pragma unroll
        for (int mi = 0; mi < 4; ++mi) {
            long long row0 = m0 + wm0 + mi * 16 + quad * 4;
            #pragma unroll
            for (int ni = 0; ni < 4; ++ni) {
                long long col = n0 + wn0 + ni * 16 + l15;
                #pragma unroll
                for (int r = 0; r < 4; ++r)
                    C[(row0 + r) * (long long)LDY + col] = __float2bfloat16(acc[mi][ni][r]);
            }
        }
    } else if (!(wave & 1)) {
        // v columns (j = ni*16+l15 in [0,64), waves 0/2 cover rows 0..127) -> vt[b][j][s]
        const int b = (int)(m0 >> 11);
        const int sbase = ((int)m0 & 2047) + wm0;
        #pragma unroll
        for (int mi = 0; mi < 4; ++mi) {
            int s0 = sbase + mi * 16 + quad * 4;
            #pragma unroll
            for (int ni = 0; ni < 4; ++ni) {
                int j = ni * 16 + l15;
                union { bf16 h[4]; ushort4 u; } cv;
                #pragma unroll
                for (int r = 0; r < 4; ++r)
                    cv.h[r] = __float2bfloat16(acc[mi][ni][r]);
                *reinterpret_cast<ushort4*>(vt + ((long long)(b * DVV + j)) * SS + s0) = cv.u;
            }
        }
    }
}

// ---------------- fused causal attention tile (K=512: scores = y·x^T) ----------------
__global__ __launch_bounds__(512) void attn_fused(const bf16* __restrict__ yv,
                                                  const bf16* __restrict__ xb,
                                                  const bf16* __restrict__ vt,
                                                  bf16* __restrict__ part,
                                                  float* __restrict__ stats) {
    constexpr int BK = 64;
    constexpr float SCALE = 0.022097086912079608f;   // 1/sqrt(2048) — dim_k unchanged

    __shared__ __align__(16) char smem[65536];
    unsigned short* As = (unsigned short*)smem;             // [2][8192] QK staging
    unsigned short* Bs = (unsigned short*)(smem + 32768);   // [2][8192]
    unsigned short* Ps = (unsigned short*)smem;             // [128][136] P~ (overlay, post-QK)
    unsigned short* Vs = (unsigned short*)(smem + 34816);   // [64][136]  V chunk
    float* smax = (float*)(smem + 52224);                   // [128][2]
    float* ssum = (float*)(smem + 53248);                   // [128][2]

    // rectangular causal fold
    int T2 = (int)gridDim.y * 2;
    int xx = blockIdx.x, rr = blockIdx.y;
    int bx, by;
    if (xx <= rr) { by = rr; bx = xx; }
    else          { by = T2 - 1 - rr; bx = xx - rr - 1; }
    const int b = blockIdx.z;

    const bf16* A  = yv + (long long)b * SS * LDY;           // y rows (q role)
    const bf16* Bt = xb + (long long)b * SS * 512;           // x rows (k role)

    const int tid = threadIdx.x;
    const int lane = tid & 63, wave = tid >> 6;
    const long long m0 = (long long)by * 128;
    const long long n0 = (long long)bx * 128;

    const int rIn = lane >> 3;
    const int cSwz = ((lane & 7) ^ rIn) * 8;
    const int wm0 = (wave >> 1) * 32, wn0 = (wave & 1) * 64;
    const int l15 = lane & 15, quad = lane >> 4;
    const int sw7 = l15 & 7;

    floatx4 acc[2][4] = {};

    auto issue = [&](int buf, int k0) {
        #pragma unroll
        for (int t0 = 0; t0 < 4; ++t0) {
            int t = t0 * 8 + wave;
            if (t < 16)
                async_copy16(A + (m0 + t * 8 + rIn) * (long long)LDY + k0 + cSwz,
                             &As[buf * 8192 + t * 512]);
            else
                async_copy16(Bt + (n0 + (t - 16) * 8 + rIn) * 512LL + k0 + cSwz,
                             &Bs[buf * 8192 + (t - 16) * 512]);
        }
    };

    issue(0, 0);
    __syncthreads();
    for (int it = 0; it < DIN / BK; ++it) {      // 8 iterations (K=512)
        const int cur = it & 1;
        if (it + 1 < DIN / BK) issue(cur ^ 1, (it + 1) * BK);
        #pragma unroll
        for (int sk = 0; sk < 2; ++sk) {
            const int rchunk = ((sk << 2) | quad) ^ sw7;
            bf16x8 af[2], bfr[4];
            #pragma unroll
            for (int mi = 0; mi < 2; ++mi)
                af[mi] = *reinterpret_cast<const bf16x8*>(
                    &As[cur * 8192 + (wm0 + mi * 16 + l15) * BK + rchunk * 8]);
            #pragma unroll
            for (int ni = 0; ni < 4; ++ni)
                bfr[ni] = *reinterpret_cast<const bf16x8*>(
                    &Bs[cur * 8192 + (wn0 + ni * 16 + l15) * BK + rchunk * 8]);
            #pragma unroll
            for (int mi = 0; mi < 2; ++mi)
                #pragma unroll
                for (int ni = 0; ni < 4; ++ni)
                    acc[mi][ni] = __builtin_amdgcn_mfma_f32_16x16x32_bf16(af[mi], bfr[ni],
                                                                          acc[mi][ni], 0, 0, 0);
        }
        __syncthreads();
    }
    // QK done. S in acc, C-layout: row=wm0+mi*16+quad*4+r, col=wn0+ni*16+l15.

    // scale + causal mask (diagonal tile only)
    #pragma unroll
    for (int mi = 0; mi < 2; ++mi)
        #pragma unroll
        for (int ni = 0; ni < 4; ++ni)
            #pragma unroll
            for (int r = 0; r < 4; ++r) {
                float v = acc[mi][ni][r] * SCALE;
                if (bx == by) {
                    int row = wm0 + mi * 16 + quad * 4 + r;
                    int col = wn0 + ni * 16 + l15;
                    if (col > row) v = -INFINITY;
                }
                acc[mi][ni][r] = v;
            }

    // row max within tile
    float rmax[2][4];
    #pragma unroll
    for (int mi = 0; mi < 2; ++mi)
        #pragma unroll
        for (int r = 0; r < 4; ++r) {
            float m = fmaxf(fmaxf(acc[mi][0][r], acc[mi][1][r]),
                            fmaxf(acc[mi][2][r], acc[mi][3][r]));
            #pragma unroll
            for (int msk = 8; msk >= 1; msk >>= 1) m = fmaxf(m, __shfl_xor(m, msk));
            rmax[mi][r] = m;
            if (l15 == 0) smax[(wm0 + mi * 16 + quad * 4 + r) * 2 + (wave & 1)] = m;
        }
    __syncthreads();
    #pragma unroll
    for (int mi = 0; mi < 2; ++mi)
        #pragma unroll
        for (int r = 0; r < 4; ++r) {
            int row = wm0 + mi * 16 + quad * 4 + r;
            rmax[mi][r] = fmaxf(smax[row * 2], smax[row * 2 + 1]);
        }

    // exp + row sums; write P~ to padded LDS
    #pragma unroll
    for (int mi = 0; mi < 2; ++mi)
        #pragma unroll
        for (int r = 0; r < 4; ++r) {
            float s = 0.f;
            #pragma unroll
            for (int ni = 0; ni < 4; ++ni) {
                float p = __expf(acc[mi][ni][r] - rmax[mi][r]);
                acc[mi][ni][r] = p;
                s += p;
            }
            #pragma unroll
            for (int msk = 8; msk >= 1; msk >>= 1) s += __shfl_xor(s, msk);
            if (l15 == 0) ssum[(wm0 + mi * 16 + quad * 4 + r) * 2 + (wave & 1)] = s;
        }
    #pragma unroll
    for (int mi = 0; mi < 2; ++mi) {
        int row = wm0 + mi * 16 + quad * 4;
        #pragma unroll
        for (int ni = 0; ni < 4; ++ni) {
            int col = wn0 + ni * 16 + l15;
            #pragma unroll
            for (int r = 0; r < 4; ++r)
                Ps[(row + r) * 136 + col] = (unsigned short)__bfloat16_as_ushort(__float2bfloat16(acc[mi][ni][r]));
        }
    }

    // stage V chunk: Vs[j][k] = vt[b][j][n0+k], xor-swizzled 16B chunks
    #pragma unroll
    for (int p = 0; p < 2; ++p) {
        int j = (tid >> 4) + p * 32;
        int ch = tid & 15;
        uint4 v = *reinterpret_cast<const uint4*>(
            vt + ((long long)b * DVV + j) * SS + n0 + ch * 8);
        *reinterpret_cast<uint4*>(&Vs[j * 136 + ((ch ^ (j & 7)) * 8)]) = v;
    }
    __syncthreads();

    // per-row stats out (m, l)
    if (tid < 128) {
        float m = fmaxf(smax[tid * 2], smax[tid * 2 + 1]);
        float l = ssum[tid * 2] + ssum[tid * 2 + 1];
        long long o = (((long long)b * 16 + bx) * SS + m0 + tid) * 2;
        stats[o] = m;
        stats[o + 1] = l;
    }

    // O' = P~ . V  (M=128, N=64, K=128): wave-tile 16 rows x 64 cols
    const int wmv = wave * 16;
    floatx4 accO[4] = {};
    #pragma unroll
    for (int sk = 0; sk < 4; ++sk) {
        bf16x8 af = *reinterpret_cast<const bf16x8*>(
            &Ps[(wmv + l15) * 136 + sk * 32 + quad * 8]);
        #pragma unroll
        for (int ni = 0; ni < 4; ++ni) {
            bf16x8 bfv = *reinterpret_cast<const bf16x8*>(
                &Vs[(ni * 16 + l15) * 136 + ((((sk << 2) | quad)) ^ sw7) * 8]);
            accO[ni] = __builtin_amdgcn_mfma_f32_16x16x32_bf16(af, bfv, accO[ni], 0, 0, 0);
        }
    }
    #pragma unroll
    for (int ni = 0; ni < 4; ++ni)
        #pragma unroll
        for (int r = 0; r < 4; ++r)
            part[(((long long)b * 16 + bx) * SS + m0 + wmv + quad * 4 + r) * 64 + ni * 16 + l15]
                = __float2bfloat16(accO[ni][r]);
}

// ---------------- combine k-tile partials (vectorized x8 bf16 loads) ----------------
__global__ __launch_bounds__(256) void combine(const bf16* __restrict__ part,
                                               const float* __restrict__ stats,
                                               float* __restrict__ out) {
    int tid = blockIdx.x * 256 + threadIdx.x;   // over 8192*8
    int row = tid >> 3;
    int col8 = (tid & 7) * 8;
    int b = row >> 11, s = row & (SS - 1);
    int nt = (s >> 7) + 1;                      // live k-tiles for this row

    float m[16], l[16], M = -INFINITY;
    #pragma unroll
    for (int t = 0; t < 16; ++t)
        if (t < nt) {
            long long o = (((long long)b * 16 + t) * SS + s) * 2;
            m[t] = stats[o];
            l[t] = stats[o + 1];
            M = fmaxf(M, m[t]);
        }
    float O[8] = {};
    float L = 0.f;
    #pragma unroll
    for (int t = 0; t < 16; ++t)
        if (t < nt) {
            float wgt = __expf(m[t] - M);
            L += wgt * l[t];
            union { uint4 q; unsigned short u[8]; } ld;
            ld.q = *reinterpret_cast<const uint4*>(
                part + (((long long)b * 16 + t) * SS + s) * 64 + col8);
            #pragma unroll
            for (int j = 0; j < 8; ++j)
                O[j] += wgt * __uint_as_float((unsigned)ld.u[j] << 16);
        }
    float rinv = 1.0f / L;
    float4 o0 = {O[0] * rinv, O[1] * rinv, O[2] * rinv, O[3] * rinv};
    float4 o1 = {O[4] * rinv, O[5] * rinv, O[6] * rinv, O[7] * rinv};
    float4* dst = reinterpret_cast<float4*>(out + (long long)row * 64 + col8);
    dst[0] = o0;
    dst[1] = o1;
}

extern "C" void kernel_launch(void* const* d_in, const int* in_sizes, int n_in,
                              void* d_out, int out_size, void* d_ws, size_t ws_size,
                              hipStream_t stream) {
    const float* x  = (const float*)d_in[0];
    const float* Wq = (const float*)d_in[1];
    const float* Wk = (const float*)d_in[2];
    const float* Wv = (const float*)d_in[3];
    float* out = (float*)d_out;

    char* w = (char*)d_ws;
    bf16* xb   = (bf16*)(w + XB_OFF);
    bf16* wqb  = (bf16*)(w + WQB_OFF);
    bf16* wkb  = (bf16*)(w + WKB_OFF);
    bf16* wt2  = (bf16*)(w + WT2_OFF);
    float* mtp = (float*)(w + MTP_OFF);
    bf16* yv   = (bf16*)(w + YV_OFF);
    bf16* vt   = (bf16*)(w + VT_OFF);
    bf16* part = (bf16*)(w + PRT_OFF);
    float* stats = (float*)(w + STA_OFF);

    // 1. fused prep: x->xb, Wq/Wk->bf16, Wv->wt2 rows 512..575 (transposed)
    prep<<<6176, 256, 0, stream>>>(x, Wq, Wk, Wv, xb, wqb, wkb, wt2);

    // 2. Mt = Wk·Wq^T [512x512] (split-K 8 partials + reduce) -> wt2 rows 0..511
    gemm_mt<<<dim3(4, 4, 8), 256, 0, stream>>>(wkb, wqb, mtp);
    reduce_mt<<<65536 / 256, 256, 0, stream>>>((const float4*)mtp, wt2);

    // 3. yv = xb·wt2^T (y cols) + vt written transposed directly from the v N-tile
    gemm_proj<<<dim3(LDY / 128, ROWS / 128, 1), 256, 0, stream>>>(xb, wt2, yv, vt);

    // 4. fused attention tiles: scores = y·x^T (K=512), softmax, P~V
    attn_fused<<<dim3(SS / 128 + 1, SS / 256, BB), 512, 0, stream>>>(yv, xb, vt, part, stats);

    // 5. combine partials -> out
    combine<<<ROWS * 8 / 256, 256, 0, stream>>>(part, stats, out);
}

// Round 2
// 144.159 us; speedup vs baseline: 1.0666x; 1.0187x over previous
//
#include <hip/hip_runtime.h>
#include <hip/hip_bf16.h>
#include <math.h>

using bf16 = __hip_bfloat16;
typedef __bf16 bf16x8 __attribute__((ext_vector_type(8)));
typedef float floatx4 __attribute__((ext_vector_type(4)));

// Problem dims
constexpr int BB = 4, SS = 2048, DIN = 512, DKK = 2048, DVV = 64;
constexpr int ROWS = BB * SS;          // 8192
constexpr int LDY = 640;               // yv row: y(512) | pad(128, garbage ok)

// ---- workspace layout (bytes) ----
constexpr size_t XB_OFF  = 0;                          // bf16 xb  [8192][512]   (8 MB)
constexpr size_t WQB_OFF = XB_OFF  + 8388608;          // bf16 wqb [512][2048]   (2 MB)
constexpr size_t WKB_OFF = WQB_OFF + 2097152;          // bf16 wkb [512][2048]   (2 MB)
constexpr size_t WT2_OFF = WKB_OFF + 2097152;          // bf16 wt2 [640][512]
constexpr size_t MTP_OFF = WT2_OFF + 655360;           // fp32 mt partials [8][512][512] (8 MB)
constexpr size_t YV_OFF  = MTP_OFF + 8388608;          // bf16 yv  [8192][640]   (10 MB)
constexpr size_t VT_OFF  = YV_OFF  + 10485760;         // bf16 vt  [4][64][2048] (1 MB)
constexpr size_t PRT_OFF = VT_OFF  + 1048576;          // bf16 O' partials [4][16][2048][64] (16 MB)
constexpr size_t STA_OFF = PRT_OFF + 16777216;         // fp32 stats [4][16][2048][2] (1 MB)

__device__ __forceinline__ void async_copy16(const bf16* g, const unsigned short* l) {
    __builtin_amdgcn_global_load_lds((const __attribute__((address_space(1))) void*)g,
                                     (__attribute__((address_space(3))) void*)l, 16, 0, 0);
}

// ---------------- fused prep: convert x | convert Wq,Wk | transpose Wv ----------------
__global__ __launch_bounds__(256) void prep(const float* __restrict__ x,
                                            const float* __restrict__ Wq,
                                            const float* __restrict__ Wk,
                                            const float* __restrict__ Wv,
                                            bf16* __restrict__ xb,
                                            bf16* __restrict__ wqb,
                                            bf16* __restrict__ wkb,
                                            bf16* __restrict__ wt2) {
    __shared__ float tile[32][33];
    const int bid = blockIdx.x;
    const int tid = threadIdx.x;

    if (bid < 4096) {
        int i = bid * 256 + tid;                     // over 1048576 float4 groups
        float4 v = reinterpret_cast<const float4*>(x)[i];
        union { bf16 h[4]; ushort4 u; } cv;
        cv.h[0] = __float2bfloat16(v.x);
        cv.h[1] = __float2bfloat16(v.y);
        cv.h[2] = __float2bfloat16(v.z);
        cv.h[3] = __float2bfloat16(v.w);
        reinterpret_cast<ushort4*>(xb)[i] = cv.u;
    } else if (bid < 6144) {
        int i = (bid - 4096) * 256 + tid;            // over 524288 float4 groups
        const float* src = (i < 262144) ? Wq : Wk;
        bf16* dst = (i < 262144) ? wqb : wkb;
        int j = (i < 262144) ? i : i - 262144;
        float4 v = reinterpret_cast<const float4*>(src)[j];
        union { bf16 h[4]; ushort4 u; } cv;
        cv.h[0] = __float2bfloat16(v.x);
        cv.h[1] = __float2bfloat16(v.y);
        cv.h[2] = __float2bfloat16(v.z);
        cv.h[3] = __float2bfloat16(v.w);
        reinterpret_cast<ushort4*>(dst)[j] = cv.u;
    } else {
        int idx = bid - 6144;                        // 0..31
        int n0 = (idx & 1) * 32;
        int k0 = (idx >> 1) * 32;
        int nn = tid & 31, kk8 = tid >> 5;
        #pragma unroll
        for (int p = 0; p < 4; ++p) {
            int k = p * 8 + kk8;
            tile[k][nn] = Wv[(long long)(k0 + k) * 64 + n0 + nn];
        }
        __syncthreads();
        int kk = tid & 31, nn8 = tid >> 5;
        #pragma unroll
        for (int p = 0; p < 4; ++p) {
            int n = p * 8 + nn8;
            wt2[(long long)(512 + n0 + n) * 512 + k0 + kk] = __float2bfloat16(tile[kk][n]);
        }
    }
}

// ---------------- Mt partial GEMM: Mt[j][i] = sum_n wkb[j][n]*wqb[i][n], split-K 8 ----------------
// XCD-swizzled z-major: each XCD owns one split-K plane (its 512 KB k-chunk L2-resident).
__global__ __launch_bounds__(256) void gemm_mt(const bf16* __restrict__ A,
                                               const bf16* __restrict__ Bt,
                                               float* __restrict__ Cp) {
    __shared__ __align__(16) unsigned short As[128 * 64];
    __shared__ __align__(16) unsigned short Bs[128 * 64];

    const int tid = threadIdx.x;
    const int lane = tid & 63, wave = tid >> 6;

    // bijective XCD swizzle: 128 blocks, q = 16
    const int wg = (blockIdx.x & 7) * 16 + (blockIdx.x >> 3);
    const int z = wg >> 4;               // split-K plane 0..7
    const int tile = wg & 15;
    const long long m0 = (long long)(tile >> 2) * 128;
    const long long n0 = (long long)(tile & 3) * 128;
    const int koff = z * 256;

    const int rIn = lane >> 3;
    const int cSwz = ((lane & 7) ^ rIn) * 8;
    const int wm0 = (wave >> 1) * 64, wn0 = (wave & 1) * 64;
    const int l15 = lane & 15, quad = lane >> 4;
    const int sw7 = l15 & 7;

    floatx4 acc[4][4] = {};

    for (int k0 = koff; k0 < koff + 256; k0 += 64) {
        #pragma unroll
        for (int t0 = 0; t0 < 8; ++t0) {
            int t = t0 * 4 + wave;
            if (t < 16)
                async_copy16(A + (m0 + t * 8 + rIn) * 2048LL + k0 + cSwz, &As[t * 512]);
            else
                async_copy16(Bt + (n0 + (t - 16) * 8 + rIn) * 2048LL + k0 + cSwz, &Bs[(t - 16) * 512]);
        }
        __syncthreads();
        #pragma unroll
        for (int sk = 0; sk < 2; ++sk) {
            const int rchunk = (((sk << 2) | quad) ^ sw7) * 8;
            bf16x8 af[4], bfr[4];
            #pragma unroll
            for (int mi = 0; mi < 4; ++mi)
                af[mi] = *reinterpret_cast<const bf16x8*>(&As[(wm0 + mi * 16 + l15) * 64 + rchunk]);
            #pragma unroll
            for (int ni = 0; ni < 4; ++ni)
                bfr[ni] = *reinterpret_cast<const bf16x8*>(&Bs[(wn0 + ni * 16 + l15) * 64 + rchunk]);
            #pragma unroll
            for (int mi = 0; mi < 4; ++mi)
                #pragma unroll
                for (int ni = 0; ni < 4; ++ni)
                    acc[mi][ni] = __builtin_amdgcn_mfma_f32_16x16x32_bf16(af[mi], bfr[ni],
                                                                          acc[mi][ni], 0, 0, 0);
        }
        __syncthreads();
    }

    float* C = Cp + (long long)z * 262144;
    #pragma unroll
    for (int mi = 0; mi < 4; ++mi) {
        long long row0 = m0 + wm0 + mi * 16 + quad * 4;
        #pragma unroll
        for (int ni = 0; ni < 4; ++ni) {
            long long col = n0 + wn0 + ni * 16 + l15;
            #pragma unroll
            for (int r = 0; r < 4; ++r)
                C[(row0 + r) * 512 + col] = acc[mi][ni][r];
        }
    }
}

// ---------------- reduce Mt partials -> wt2 rows 0..511 (bf16) ----------------
__global__ __launch_bounds__(256) void reduce_mt(const float4* __restrict__ part,
                                                 bf16* __restrict__ wt2) {
    int i = blockIdx.x * 256 + threadIdx.x;          // over 65536 float4 groups
    float4 s = {0.f, 0.f, 0.f, 0.f};
    #pragma unroll
    for (int t = 0; t < 8; ++t) {
        float4 a = part[(long long)t * 65536 + i];
        s.x += a.x; s.y += a.y; s.z += a.z; s.w += a.w;
    }
    union { bf16 h[4]; ushort4 u; } cv;
    cv.h[0] = __float2bfloat16(s.x);
    cv.h[1] = __float2bfloat16(s.y);
    cv.h[2] = __float2bfloat16(s.z);
    cv.h[3] = __float2bfloat16(s.w);
    reinterpret_cast<ushort4*>(wt2)[i] = cv.u;
}

// ---------------- yv GEMM: yv[8192][0..512) = xb . wt2^T, K=512 ----------------
// XCD-swizzled m-major: each XCD gets 8 complete m-panels (A fetched once per chip,
// wt2 L2-resident per XCD). N-tile 4 writes v TRANSPOSED directly to vt.
__global__ __launch_bounds__(256) void gemm_proj(const bf16* __restrict__ A,
                                                 const bf16* __restrict__ Bt,
                                                 bf16* __restrict__ C,
                                                 bf16* __restrict__ vt) {
    __shared__ __align__(16) unsigned short As[128 * 64];
    __shared__ __align__(16) unsigned short Bs[128 * 64];

    const int tid = threadIdx.x;
    const int lane = tid & 63, wave = tid >> 6;

    // bijective XCD swizzle: 320 blocks, q = 40; m-major enumeration
    const int wg = (blockIdx.x & 7) * 40 + (blockIdx.x >> 3);
    const long long m0 = (long long)(wg / 5) * 128;
    const long long n0 = (long long)(wg % 5) * 128;

    const int rIn = lane >> 3;
    const int cSwz = ((lane & 7) ^ rIn) * 8;
    const int wm0 = (wave >> 1) * 64, wn0 = (wave & 1) * 64;
    const int l15 = lane & 15, quad = lane >> 4;
    const int sw7 = l15 & 7;

    floatx4 acc[4][4] = {};

    for (int k0 = 0; k0 < DIN; k0 += 64) {
        #pragma unroll
        for (int t0 = 0; t0 < 8; ++t0) {
            int t = t0 * 4 + wave;
            if (t < 16)
                async_copy16(A + (m0 + t * 8 + rIn) * (long long)DIN + k0 + cSwz, &As[t * 512]);
            else
                async_copy16(Bt + (n0 + (t - 16) * 8 + rIn) * (long long)DIN + k0 + cSwz, &Bs[(t - 16) * 512]);
        }
        __syncthreads();
        #pragma unroll
        for (int sk = 0; sk < 2; ++sk) {
            const int rchunk = (((sk << 2) | quad) ^ sw7) * 8;
            bf16x8 af[4], bfr[4];
            #pragma unroll
            for (int mi = 0; mi < 4; ++mi)
                af[mi] = *reinterpret_cast<const bf16x8*>(&As[(wm0 + mi * 16 + l15) * 64 + rchunk]);
            #pragma unroll
            for (int ni = 0; ni < 4; ++ni)
                bfr[ni] = *reinterpret_cast<const bf16x8*>(&Bs[(wn0 + ni * 16 + l15) * 64 + rchunk]);
            #pragma unroll
            for (int mi = 0; mi < 4; ++mi)
                #pragma unroll
                for (int ni = 0; ni < 4; ++ni)
                    acc[mi][ni] = __builtin_amdgcn_mfma_f32_16x16x32_bf16(af[mi], bfr[ni],
                                                                          acc[mi][ni], 0, 0, 0);
        }
        __syncthreads();
    }

    if (n0 < 512) {
        // y columns -> yv (row stride LDY)
        #pragma unroll
        for (int mi = 0; mi < 4; ++mi) {
            long long row0 = m0 + wm0 + mi * 16 + quad * 4;
            #pragma unroll
            for (int ni = 0; ni < 4; ++ni) {
                long long col = n0 + wn0 + ni * 16 + l15;
                #pragma unroll
                for (int r = 0; r < 4; ++r)
                    C[(row0 + r) * (long long)LDY + col] = __float2bfloat16(acc[mi][ni][r]);
            }
        }
    } else if (!(wave & 1)) {
        // v columns (j = ni*16+l15 in [0,64)) -> vt[b][j][s] transposed
        const int b = (int)(m0 >> 11);
        const int sbase = ((int)m0 & 2047) + wm0;
        #pragma unroll
        for (int mi = 0; mi < 4; ++mi) {
            int s0 = sbase + mi * 16 + quad * 4;
            #pragma unroll
            for (int ni = 0; ni < 4; ++ni) {
                int j = ni * 16 + l15;
                union { bf16 h[4]; ushort4 u; } cv;
                #pragma unroll
                for (int r = 0; r < 4; ++r)
                    cv.h[r] = __float2bfloat16(acc[mi][ni][r]);
                *reinterpret_cast<ushort4*>(vt + ((long long)(b * DVV + j)) * SS + s0) = cv.u;
            }
        }
    }
}

// ---------------- fused causal attention tile (K=512: scores = y·x^T) ----------------
// Grid (136, 1, 4): causal lower-triangle enumerated row-major, XCD-swizzled so each
// XCD's 17 consecutive tiles share the same by (y A-panel L2-resident).
__global__ __launch_bounds__(512) void attn_fused(const bf16* __restrict__ yv,
                                                  const bf16* __restrict__ xb,
                                                  const bf16* __restrict__ vt,
                                                  bf16* __restrict__ part,
                                                  float* __restrict__ stats) {
    constexpr int BK = 64;
    constexpr float SCALE = 0.022097086912079608f;   // 1/sqrt(2048)

    __shared__ __align__(16) char smem[65536];
    unsigned short* As = (unsigned short*)smem;             // [2][8192] QK staging
    unsigned short* Bs = (unsigned short*)(smem + 32768);   // [2][8192]
    unsigned short* Ps = (unsigned short*)smem;             // [128][136] P~ (overlay, post-QK)
    unsigned short* Vs = (unsigned short*)(smem + 34816);   // [64][136]  V chunk
    float* smax = (float*)(smem + 52224);                   // [128][2]
    float* ssum = (float*)(smem + 53248);                   // [128][2]

    // XCD-aware causal tile decode (136 = 8 * 17, bijective)
    const int wg = (blockIdx.x & 7) * 17 + (blockIdx.x >> 3);
    int by = (int)((sqrtf(8.f * (float)wg + 1.f) - 1.f) * 0.5f);
    while ((by + 1) * (by + 2) / 2 <= wg) ++by;
    while (by * (by + 1) / 2 > wg) --by;
    const int bx = wg - by * (by + 1) / 2;
    const int b = blockIdx.z;

    const bf16* A  = yv + (long long)b * SS * LDY;           // y rows (q role)
    const bf16* Bt = xb + (long long)b * SS * 512;           // x rows (k role)

    const int tid = threadIdx.x;
    const int lane = tid & 63, wave = tid >> 6;
    const long long m0 = (long long)by * 128;
    const long long n0 = (long long)bx * 128;

    const int rIn = lane >> 3;
    const int cSwz = ((lane & 7) ^ rIn) * 8;
    const int wm0 = (wave >> 1) * 32, wn0 = (wave & 1) * 64;
    const int l15 = lane & 15, quad = lane >> 4;
    const int sw7 = l15 & 7;

    floatx4 acc[2][4] = {};

    // T14: prefetch V chunk to registers (ds_write after QK when Vs overlay is free)
    uint4 vreg[2];
    #pragma unroll
    for (int p = 0; p < 2; ++p) {
        int j = (tid >> 4) + p * 32;
        int ch = tid & 15;
        vreg[p] = *reinterpret_cast<const uint4*>(
            vt + ((long long)b * DVV + j) * SS + n0 + ch * 8);
    }

    auto issue = [&](int buf, int k0) {
        #pragma unroll
        for (int t0 = 0; t0 < 4; ++t0) {
            int t = t0 * 8 + wave;
            if (t < 16)
                async_copy16(A + (m0 + t * 8 + rIn) * (long long)LDY + k0 + cSwz,
                             &As[buf * 8192 + t * 512]);
            else
                async_copy16(Bt + (n0 + (t - 16) * 8 + rIn) * 512LL + k0 + cSwz,
                             &Bs[buf * 8192 + (t - 16) * 512]);
        }
    };

    issue(0, 0);
    __syncthreads();
    for (int it = 0; it < DIN / BK; ++it) {      // 8 iterations (K=512)
        const int cur = it & 1;
        if (it + 1 < DIN / BK) issue(cur ^ 1, (it + 1) * BK);
        #pragma unroll
        for (int sk = 0; sk < 2; ++sk) {
            const int rchunk = ((sk << 2) | quad) ^ sw7;
            bf16x8 af[2], bfr[4];
            #pragma unroll
            for (int mi = 0; mi < 2; ++mi)
                af[mi] = *reinterpret_cast<const bf16x8*>(
                    &As[cur * 8192 + (wm0 + mi * 16 + l15) * BK + rchunk * 8]);
            #pragma unroll
            for (int ni = 0; ni < 4; ++ni)
                bfr[ni] = *reinterpret_cast<const bf16x8*>(
                    &Bs[cur * 8192 + (wn0 + ni * 16 + l15) * BK + rchunk * 8]);
            #pragma unroll
            for (int mi = 0; mi < 2; ++mi)
                #pragma unroll
                for (int ni = 0; ni < 4; ++ni)
                    acc[mi][ni] = __builtin_amdgcn_mfma_f32_16x16x32_bf16(af[mi], bfr[ni],
                                                                          acc[mi][ni], 0, 0, 0);
        }
        __syncthreads();
    }
    // QK done. S in acc, C-layout: row=wm0+mi*16+quad*4+r, col=wn0+ni*16+l15.

    // scale + causal mask (diagonal tile only)
    #pragma unroll
    for (int mi = 0; mi < 2; ++mi)
        #pragma unroll
        for (int ni = 0; ni < 4; ++ni)
            #pragma unroll
            for (int r = 0; r < 4; ++r) {
                float v = acc[mi][ni][r] * SCALE;
                if (bx == by) {
                    int row = wm0 + mi * 16 + quad * 4 + r;
                    int col = wn0 + ni * 16 + l15;
                    if (col > row) v = -INFINITY;
                }
                acc[mi][ni][r] = v;
            }

    // row max within tile
    float rmax[2][4];
    #pragma unroll
    for (int mi = 0; mi < 2; ++mi)
        #pragma unroll
        for (int r = 0; r < 4; ++r) {
            float m = fmaxf(fmaxf(acc[mi][0][r], acc[mi][1][r]),
                            fmaxf(acc[mi][2][r], acc[mi][3][r]));
            #pragma unroll
            for (int msk = 8; msk >= 1; msk >>= 1) m = fmaxf(m, __shfl_xor(m, msk));
            rmax[mi][r] = m;
            if (l15 == 0) smax[(wm0 + mi * 16 + quad * 4 + r) * 2 + (wave & 1)] = m;
        }
    __syncthreads();
    #pragma unroll
    for (int mi = 0; mi < 2; ++mi)
        #pragma unroll
        for (int r = 0; r < 4; ++r) {
            int row = wm0 + mi * 16 + quad * 4 + r;
            rmax[mi][r] = fmaxf(smax[row * 2], smax[row * 2 + 1]);
        }

    // exp + row sums; write P~ to padded LDS
    #pragma unroll
    for (int mi = 0; mi < 2; ++mi)
        #pragma unroll
        for (int r = 0; r < 4; ++r) {
            float s = 0.f;
            #pragma unroll
            for (int ni = 0; ni < 4; ++ni) {
                float p = __expf(acc[mi][ni][r] - rmax[mi][r]);
                acc[mi][ni][r] = p;
                s += p;
            }
            #pragma unroll
            for (int msk = 8; msk >= 1; msk >>= 1) s += __shfl_xor(s, msk);
            if (l15 == 0) ssum[(wm0 + mi * 16 + quad * 4 + r) * 2 + (wave & 1)] = s;
        }
    #pragma unroll
    for (int mi = 0; mi < 2; ++mi) {
        int row = wm0 + mi * 16 + quad * 4;
        #pragma unroll
        for (int ni = 0; ni < 4; ++ni) {
            int col = wn0 + ni * 16 + l15;
            #pragma unroll
            for (int r = 0; r < 4; ++r)
                Ps[(row + r) * 136 + col] = (unsigned short)__bfloat16_as_ushort(__float2bfloat16(acc[mi][ni][r]));
        }
    }

    // write prefetched V chunk: Vs[j][k], xor-swizzled 16B chunks
    #pragma unroll
    for (int p = 0; p < 2; ++p) {
        int j = (tid >> 4) + p * 32;
        int ch = tid & 15;
        *reinterpret_cast<uint4*>(&Vs[j * 136 + ((ch ^ (j & 7)) * 8)]) = vreg[p];
    }
    __syncthreads();

    // per-row stats out (m, l)
    if (tid < 128) {
        float m = fmaxf(smax[tid * 2], smax[tid * 2 + 1]);
        float l = ssum[tid * 2] + ssum[tid * 2 + 1];
        long long o = (((long long)b * 16 + bx) * SS + m0 + tid) * 2;
        stats[o] = m;
        stats[o + 1] = l;
    }

    // O' = P~ . V  (M=128, N=64, K=128): wave-tile 16 rows x 64 cols
    const int wmv = wave * 16;
    floatx4 accO[4] = {};
    #pragma unroll
    for (int sk = 0; sk < 4; ++sk) {
        bf16x8 af = *reinterpret_cast<const bf16x8*>(
            &Ps[(wmv + l15) * 136 + sk * 32 + quad * 8]);
        #pragma unroll
        for (int ni = 0; ni < 4; ++ni) {
            bf16x8 bfv = *reinterpret_cast<const bf16x8*>(
                &Vs[(ni * 16 + l15) * 136 + ((((sk << 2) | quad)) ^ sw7) * 8]);
            accO[ni] = __builtin_amdgcn_mfma_f32_16x16x32_bf16(af, bfv, accO[ni], 0, 0, 0);
        }
    }
    #pragma unroll
    for (int ni = 0; ni < 4; ++ni)
        #pragma unroll
        for (int r = 0; r < 4; ++r)
            part[(((long long)b * 16 + bx) * SS + m0 + wmv + quad * 4 + r) * 64 + ni * 16 + l15]
                = __float2bfloat16(accO[ni][r]);
}

// ---------------- combine k-tile partials (vectorized x8 bf16 loads) ----------------
__global__ __launch_bounds__(256) void combine(const bf16* __restrict__ part,
                                               const float* __restrict__ stats,
                                               float* __restrict__ out) {
    int tid = blockIdx.x * 256 + threadIdx.x;   // over 8192*8
    int row = tid >> 3;
    int col8 = (tid & 7) * 8;
    int b = row >> 11, s = row & (SS - 1);
    int nt = (s >> 7) + 1;                      // live k-tiles for this row

    float m[16], l[16], M = -INFINITY;
    #pragma unroll
    for (int t = 0; t < 16; ++t)
        if (t < nt) {
            long long o = (((long long)b * 16 + t) * SS + s) * 2;
            m[t] = stats[o];
            l[t] = stats[o + 1];
            M = fmaxf(M, m[t]);
        }
    float O[8] = {};
    float L = 0.f;
    #pragma unroll
    for (int t = 0; t < 16; ++t)
        if (t < nt) {
            float wgt = __expf(m[t] - M);
            L += wgt * l[t];
            union { uint4 q; unsigned short u[8]; } ld;
            ld.q = *reinterpret_cast<const uint4*>(
                part + (((long long)b * 16 + t) * SS + s) * 64 + col8);
            #pragma unroll
            for (int j = 0; j < 8; ++j)
                O[j] += wgt * __uint_as_float((unsigned)ld.u[j] << 16);
        }
    float rinv = 1.0f / L;
    float4 o0 = {O[0] * rinv, O[1] * rinv, O[2] * rinv, O[3] * rinv};
    float4 o1 = {O[4] * rinv, O[5] * rinv, O[6] * rinv, O[7] * rinv};
    float4* dst = reinterpret_cast<float4*>(out + (long long)row * 64 + col8);
    dst[0] = o0;
    dst[1] = o1;
}

extern "C" void kernel_launch(void* const* d_in, const int* in_sizes, int n_in,
                              void* d_out, int out_size, void* d_ws, size_t ws_size,
                              hipStream_t stream) {
    const float* x  = (const float*)d_in[0];
    const float* Wq = (const float*)d_in[1];
    const float* Wk = (const float*)d_in[2];
    const float* Wv = (const float*)d_in[3];
    float* out = (float*)d_out;

    char* w = (char*)d_ws;
    bf16* xb   = (bf16*)(w + XB_OFF);
    bf16* wqb  = (bf16*)(w + WQB_OFF);
    bf16* wkb  = (bf16*)(w + WKB_OFF);
    bf16* wt2  = (bf16*)(w + WT2_OFF);
    float* mtp = (float*)(w + MTP_OFF);
    bf16* yv   = (bf16*)(w + YV_OFF);
    bf16* vt   = (bf16*)(w + VT_OFF);
    bf16* part = (bf16*)(w + PRT_OFF);
    float* stats = (float*)(w + STA_OFF);

    // 1. fused prep: x->xb, Wq/Wk->bf16, Wv->wt2 rows 512..575 (transposed)
    prep<<<6176, 256, 0, stream>>>(x, Wq, Wk, Wv, xb, wqb, wkb, wt2);

    // 2. Mt = Wk·Wq^T [512x512] (split-K 8 partials + reduce) -> wt2 rows 0..511
    gemm_mt<<<128, 256, 0, stream>>>(wkb, wqb, mtp);
    reduce_mt<<<65536 / 256, 256, 0, stream>>>((const float4*)mtp, wt2);

    // 3. yv = xb·wt2^T (y cols) + vt written transposed directly from the v N-tile
    gemm_proj<<<320, 256, 0, stream>>>(xb, wt2, yv, vt);

    // 4. fused attention tiles: scores = y·x^T (K=512), softmax, P~V
    attn_fused<<<dim3(136, 1, BB), 512, 0, stream>>>(yv, xb, vt, part, stats);

    // 5. combine partials -> out
    combine<<<ROWS * 8 / 256, 256, 0, stream>>>(part, stats, out);
}

// Round 3
// 141.323 us; speedup vs baseline: 1.0880x; 1.0201x over previous
//
#include <hip/hip_runtime.h>
#include <hip/hip_bf16.h>
#include <math.h>

using bf16 = __hip_bfloat16;
typedef __bf16 bf16x8 __attribute__((ext_vector_type(8)));
typedef float floatx4 __attribute__((ext_vector_type(4)));

// Problem dims
constexpr int BB = 4, SS = 2048, DIN = 512, DKK = 2048, DVV = 64;
constexpr int ROWS = BB * SS;          // 8192
constexpr int LDY = 640;               // yv row: y(512) | pad(128, garbage ok)

// ---- workspace layout (bytes) ----
constexpr size_t XB_OFF  = 0;                          // bf16 xb  [8192][512]   (8 MB)
constexpr size_t WQB_OFF = XB_OFF  + 8388608;          // bf16 wqb [512][2048]   (2 MB)
constexpr size_t WKB_OFF = WQB_OFF + 2097152;          // bf16 wkb [512][2048]   (2 MB)
constexpr size_t WT2_OFF = WKB_OFF + 2097152;          // bf16 wt2 [640][512]
constexpr size_t MTP_OFF = WT2_OFF + 655360;           // fp32 mt partials [8][512][512] (8 MB)
constexpr size_t YV_OFF  = MTP_OFF + 8388608;          // bf16 yv  [8192][640]   (10 MB)
constexpr size_t VT_OFF  = YV_OFF  + 10485760;         // bf16 vt  [4][64][2048] (1 MB)
constexpr size_t PRT_OFF = VT_OFF  + 1048576;          // bf16 O' partials [4][16][2048][64] (16 MB)
constexpr size_t STA_OFF = PRT_OFF + 16777216;         // fp32 stats [4][16][2048][2] (1 MB)

__device__ __forceinline__ void async_copy16(const bf16* g, const unsigned short* l) {
    __builtin_amdgcn_global_load_lds((const __attribute__((address_space(1))) void*)g,
                                     (__attribute__((address_space(3))) void*)l, 16, 0, 0);
}

// ---------------- fused prep: convert x | convert Wq,Wk | transpose Wv ----------------
__global__ __launch_bounds__(256) void prep(const float* __restrict__ x,
                                            const float* __restrict__ Wq,
                                            const float* __restrict__ Wk,
                                            const float* __restrict__ Wv,
                                            bf16* __restrict__ xb,
                                            bf16* __restrict__ wqb,
                                            bf16* __restrict__ wkb,
                                            bf16* __restrict__ wt2) {
    __shared__ float tile[32][33];
    const int bid = blockIdx.x;
    const int tid = threadIdx.x;

    if (bid < 4096) {
        int i = bid * 256 + tid;                     // over 1048576 float4 groups
        float4 v = reinterpret_cast<const float4*>(x)[i];
        union { bf16 h[4]; ushort4 u; } cv;
        cv.h[0] = __float2bfloat16(v.x);
        cv.h[1] = __float2bfloat16(v.y);
        cv.h[2] = __float2bfloat16(v.z);
        cv.h[3] = __float2bfloat16(v.w);
        reinterpret_cast<ushort4*>(xb)[i] = cv.u;
    } else if (bid < 6144) {
        int i = (bid - 4096) * 256 + tid;            // over 524288 float4 groups
        const float* src = (i < 262144) ? Wq : Wk;
        bf16* dst = (i < 262144) ? wqb : wkb;
        int j = (i < 262144) ? i : i - 262144;
        float4 v = reinterpret_cast<const float4*>(src)[j];
        union { bf16 h[4]; ushort4 u; } cv;
        cv.h[0] = __float2bfloat16(v.x);
        cv.h[1] = __float2bfloat16(v.y);
        cv.h[2] = __float2bfloat16(v.z);
        cv.h[3] = __float2bfloat16(v.w);
        reinterpret_cast<ushort4*>(dst)[j] = cv.u;
    } else {
        int idx = bid - 6144;                        // 0..31
        int n0 = (idx & 1) * 32;
        int k0 = (idx >> 1) * 32;
        int nn = tid & 31, kk8 = tid >> 5;
        #pragma unroll
        for (int p = 0; p < 4; ++p) {
            int k = p * 8 + kk8;
            tile[k][nn] = Wv[(long long)(k0 + k) * 64 + n0 + nn];
        }
        __syncthreads();
        int kk = tid & 31, nn8 = tid >> 5;
        #pragma unroll
        for (int p = 0; p < 4; ++p) {
            int n = p * 8 + nn8;
            wt2[(long long)(512 + n0 + n) * 512 + k0 + kk] = __float2bfloat16(tile[kk][n]);
        }
    }
}

// ---------------- Mt partial GEMM: Mt[j][i] = sum_n wkb[j][n]*wqb[i][n], split-K 8 ----------------
__global__ __launch_bounds__(256) void gemm_mt(const bf16* __restrict__ A,
                                               const bf16* __restrict__ Bt,
                                               float* __restrict__ Cp) {
    __shared__ __align__(16) unsigned short As[128 * 64];
    __shared__ __align__(16) unsigned short Bs[128 * 64];

    const int tid = threadIdx.x;
    const int lane = tid & 63, wave = tid >> 6;

    // bijective XCD swizzle: 128 blocks, q = 16
    const int wg = (blockIdx.x & 7) * 16 + (blockIdx.x >> 3);
    const int z = wg >> 4;               // split-K plane 0..7
    const int tile = wg & 15;
    const long long m0 = (long long)(tile >> 2) * 128;
    const long long n0 = (long long)(tile & 3) * 128;
    const int koff = z * 256;

    const int rIn = lane >> 3;
    const int cSwz = ((lane & 7) ^ rIn) * 8;
    const int wm0 = (wave >> 1) * 64, wn0 = (wave & 1) * 64;
    const int l15 = lane & 15, quad = lane >> 4;
    const int sw7 = l15 & 7;

    floatx4 acc[4][4] = {};

    for (int k0 = koff; k0 < koff + 256; k0 += 64) {
        #pragma unroll
        for (int t0 = 0; t0 < 8; ++t0) {
            int t = t0 * 4 + wave;
            if (t < 16)
                async_copy16(A + (m0 + t * 8 + rIn) * 2048LL + k0 + cSwz, &As[t * 512]);
            else
                async_copy16(Bt + (n0 + (t - 16) * 8 + rIn) * 2048LL + k0 + cSwz, &Bs[(t - 16) * 512]);
        }
        __syncthreads();
        #pragma unroll
        for (int sk = 0; sk < 2; ++sk) {
            const int rchunk = (((sk << 2) | quad) ^ sw7) * 8;
            bf16x8 af[4], bfr[4];
            #pragma unroll
            for (int mi = 0; mi < 4; ++mi)
                af[mi] = *reinterpret_cast<const bf16x8*>(&As[(wm0 + mi * 16 + l15) * 64 + rchunk]);
            #pragma unroll
            for (int ni = 0; ni < 4; ++ni)
                bfr[ni] = *reinterpret_cast<const bf16x8*>(&Bs[(wn0 + ni * 16 + l15) * 64 + rchunk]);
            #pragma unroll
            for (int mi = 0; mi < 4; ++mi)
                #pragma unroll
                for (int ni = 0; ni < 4; ++ni)
                    acc[mi][ni] = __builtin_amdgcn_mfma_f32_16x16x32_bf16(af[mi], bfr[ni],
                                                                          acc[mi][ni], 0, 0, 0);
        }
        __syncthreads();
    }

    float* C = Cp + (long long)z * 262144;
    #pragma unroll
    for (int mi = 0; mi < 4; ++mi) {
        long long row0 = m0 + wm0 + mi * 16 + quad * 4;
        #pragma unroll
        for (int ni = 0; ni < 4; ++ni) {
            long long col = n0 + wn0 + ni * 16 + l15;
            #pragma unroll
            for (int r = 0; r < 4; ++r)
                C[(row0 + r) * 512 + col] = acc[mi][ni][r];
        }
    }
}

// ---------------- reduce Mt partials -> wt2 rows 0..511 (bf16) ----------------
__global__ __launch_bounds__(256) void reduce_mt(const float4* __restrict__ part,
                                                 bf16* __restrict__ wt2) {
    int i = blockIdx.x * 256 + threadIdx.x;          // over 65536 float4 groups
    float4 s = {0.f, 0.f, 0.f, 0.f};
    #pragma unroll
    for (int t = 0; t < 8; ++t) {
        float4 a = part[(long long)t * 65536 + i];
        s.x += a.x; s.y += a.y; s.z += a.z; s.w += a.w;
    }
    union { bf16 h[4]; ushort4 u; } cv;
    cv.h[0] = __float2bfloat16(s.x);
    cv.h[1] = __float2bfloat16(s.y);
    cv.h[2] = __float2bfloat16(s.z);
    cv.h[3] = __float2bfloat16(s.w);
    reinterpret_cast<ushort4*>(wt2)[i] = cv.u;
}

// ---------------- yv GEMM: yv[8192][0..512) = xb . wt2^T, K=512 ----------------
__global__ __launch_bounds__(256) void gemm_proj(const bf16* __restrict__ A,
                                                 const bf16* __restrict__ Bt,
                                                 bf16* __restrict__ C,
                                                 bf16* __restrict__ vt) {
    __shared__ __align__(16) unsigned short As[128 * 64];
    __shared__ __align__(16) unsigned short Bs[128 * 64];

    const int tid = threadIdx.x;
    const int lane = tid & 63, wave = tid >> 6;

    // bijective XCD swizzle: 320 blocks, q = 40; m-major enumeration
    const int wg = (blockIdx.x & 7) * 40 + (blockIdx.x >> 3);
    const long long m0 = (long long)(wg / 5) * 128;
    const long long n0 = (long long)(wg % 5) * 128;

    const int rIn = lane >> 3;
    const int cSwz = ((lane & 7) ^ rIn) * 8;
    const int wm0 = (wave >> 1) * 64, wn0 = (wave & 1) * 64;
    const int l15 = lane & 15, quad = lane >> 4;
    const int sw7 = l15 & 7;

    floatx4 acc[4][4] = {};

    for (int k0 = 0; k0 < DIN; k0 += 64) {
        #pragma unroll
        for (int t0 = 0; t0 < 8; ++t0) {
            int t = t0 * 4 + wave;
            if (t < 16)
                async_copy16(A + (m0 + t * 8 + rIn) * (long long)DIN + k0 + cSwz, &As[t * 512]);
            else
                async_copy16(Bt + (n0 + (t - 16) * 8 + rIn) * (long long)DIN + k0 + cSwz, &Bs[(t - 16) * 512]);
        }
        __syncthreads();
        #pragma unroll
        for (int sk = 0; sk < 2; ++sk) {
            const int rchunk = (((sk << 2) | quad) ^ sw7) * 8;
            bf16x8 af[4], bfr[4];
            #pragma unroll
            for (int mi = 0; mi < 4; ++mi)
                af[mi] = *reinterpret_cast<const bf16x8*>(&As[(wm0 + mi * 16 + l15) * 64 + rchunk]);
            #pragma unroll
            for (int ni = 0; ni < 4; ++ni)
                bfr[ni] = *reinterpret_cast<const bf16x8*>(&Bs[(wn0 + ni * 16 + l15) * 64 + rchunk]);
            #pragma unroll
            for (int mi = 0; mi < 4; ++mi)
                #pragma unroll
                for (int ni = 0; ni < 4; ++ni)
                    acc[mi][ni] = __builtin_amdgcn_mfma_f32_16x16x32_bf16(af[mi], bfr[ni],
                                                                          acc[mi][ni], 0, 0, 0);
        }
        __syncthreads();
    }

    if (n0 < 512) {
        // y columns -> yv (row stride LDY)
        #pragma unroll
        for (int mi = 0; mi < 4; ++mi) {
            long long row0 = m0 + wm0 + mi * 16 + quad * 4;
            #pragma unroll
            for (int ni = 0; ni < 4; ++ni) {
                long long col = n0 + wn0 + ni * 16 + l15;
                #pragma unroll
                for (int r = 0; r < 4; ++r)
                    C[(row0 + r) * (long long)LDY + col] = __float2bfloat16(acc[mi][ni][r]);
            }
        }
    } else if (!(wave & 1)) {
        // v columns (j = ni*16+l15 in [0,64)) -> vt[b][j][s] transposed
        const int b = (int)(m0 >> 11);
        const int sbase = ((int)m0 & 2047) + wm0;
        #pragma unroll
        for (int mi = 0; mi < 4; ++mi) {
            int s0 = sbase + mi * 16 + quad * 4;
            #pragma unroll
            for (int ni = 0; ni < 4; ++ni) {
                int j = ni * 16 + l15;
                union { bf16 h[4]; ushort4 u; } cv;
                #pragma unroll
                for (int r = 0; r < 4; ++r)
                    cv.h[r] = __float2bfloat16(acc[mi][ni][r]);
                *reinterpret_cast<ushort4*>(vt + ((long long)(b * DVV + j)) * SS + s0) = cv.u;
            }
        }
    }
}

// ---------------- fused causal attention tile (K=512: scores = y·x^T) ----------------
// LDS diet: 37888 B/block -> 3-4 blocks/CU co-resident (was ~80 KB -> 1 block/CU).
// QK single-buffered (cross-block TLP hides the drain); PV split into two 64-col halves
// through Ps[128][72]; accumulation order identical to the monolithic version.
__global__ __launch_bounds__(512) void attn_fused(const bf16* __restrict__ yv,
                                                  const bf16* __restrict__ xb,
                                                  const bf16* __restrict__ vt,
                                                  bf16* __restrict__ part,
                                                  float* __restrict__ stats) {
    constexpr int BK = 64;
    constexpr float SCALE = 0.022097086912079608f;   // 1/sqrt(2048)

    __shared__ __align__(16) char smem[37888];
    unsigned short* As = (unsigned short*)smem;             // [8192] QK A staging (16 KB)
    unsigned short* Bs = (unsigned short*)(smem + 16384);   // [8192] QK B staging (16 KB)
    unsigned short* Ps = (unsigned short*)smem;             // [128][72] P~ half (overlay, post-QK)
    unsigned short* Vs = (unsigned short*)(smem + 18432);   // [64][136] V chunk
    float* smax = (float*)(smem + 35840);                   // [128][2]
    float* ssum = (float*)(smem + 36864);                   // [128][2]

    // XCD-aware causal tile decode (136 = 8 * 17, bijective)
    const int wg = (blockIdx.x & 7) * 17 + (blockIdx.x >> 3);
    int by = (int)((sqrtf(8.f * (float)wg + 1.f) - 1.f) * 0.5f);
    while ((by + 1) * (by + 2) / 2 <= wg) ++by;
    while (by * (by + 1) / 2 > wg) --by;
    const int bx = wg - by * (by + 1) / 2;
    const int b = blockIdx.z;

    const bf16* A  = yv + (long long)b * SS * LDY;           // y rows (q role)
    const bf16* Bt = xb + (long long)b * SS * 512;           // x rows (k role)

    const int tid = threadIdx.x;
    const int lane = tid & 63, wave = tid >> 6;
    const long long m0 = (long long)by * 128;
    const long long n0 = (long long)bx * 128;

    const int rIn = lane >> 3;
    const int cSwz = ((lane & 7) ^ rIn) * 8;
    const int wm0 = (wave >> 1) * 32, wn0 = (wave & 1) * 64;
    const int l15 = lane & 15, quad = lane >> 4;
    const int sw7 = l15 & 7;

    floatx4 acc[2][4] = {};

    // T14: prefetch V chunk to registers (ds_write after QK when Vs overlay is free)
    uint4 vreg[2];
    #pragma unroll
    for (int p = 0; p < 2; ++p) {
        int j = (tid >> 4) + p * 32;
        int ch = tid & 15;
        vreg[p] = *reinterpret_cast<const uint4*>(
            vt + ((long long)b * DVV + j) * SS + n0 + ch * 8);
    }

    auto issue = [&](int k0) {
        #pragma unroll
        for (int t0 = 0; t0 < 4; ++t0) {
            int t = t0 * 8 + wave;
            if (t < 16)
                async_copy16(A + (m0 + t * 8 + rIn) * (long long)LDY + k0 + cSwz,
                             &As[t * 512]);
            else
                async_copy16(Bt + (n0 + (t - 16) * 8 + rIn) * 512LL + k0 + cSwz,
                             &Bs[(t - 16) * 512]);
        }
    };

    for (int it = 0; it < DIN / BK; ++it) {      // 8 iterations (K=512)
        issue(it * BK);
        __syncthreads();                          // loads landed (compiler drains vmcnt)
        __builtin_amdgcn_s_setprio(1);
        #pragma unroll
        for (int sk = 0; sk < 2; ++sk) {
            const int rchunk = ((sk << 2) | quad) ^ sw7;
            bf16x8 af[2], bfr[4];
            #pragma unroll
            for (int mi = 0; mi < 2; ++mi)
                af[mi] = *reinterpret_cast<const bf16x8*>(
                    &As[(wm0 + mi * 16 + l15) * BK + rchunk * 8]);
            #pragma unroll
            for (int ni = 0; ni < 4; ++ni)
                bfr[ni] = *reinterpret_cast<const bf16x8*>(
                    &Bs[(wn0 + ni * 16 + l15) * BK + rchunk * 8]);
            #pragma unroll
            for (int mi = 0; mi < 2; ++mi)
                #pragma unroll
                for (int ni = 0; ni < 4; ++ni)
                    acc[mi][ni] = __builtin_amdgcn_mfma_f32_16x16x32_bf16(af[mi], bfr[ni],
                                                                          acc[mi][ni], 0, 0, 0);
        }
        __builtin_amdgcn_s_setprio(0);
        __syncthreads();                          // all reads done before next issue
    }
    // QK done. S in acc, C-layout: row=wm0+mi*16+quad*4+r, col=wn0+ni*16+l15.

    // scale + causal mask (diagonal tile only)
    #pragma unroll
    for (int mi = 0; mi < 2; ++mi)
        #pragma unroll
        for (int ni = 0; ni < 4; ++ni)
            #pragma unroll
            for (int r = 0; r < 4; ++r) {
                float v = acc[mi][ni][r] * SCALE;
                if (bx == by) {
                    int row = wm0 + mi * 16 + quad * 4 + r;
                    int col = wn0 + ni * 16 + l15;
                    if (col > row) v = -INFINITY;
                }
                acc[mi][ni][r] = v;
            }

    // row max within tile
    float rmax[2][4];
    #pragma unroll
    for (int mi = 0; mi < 2; ++mi)
        #pragma unroll
        for (int r = 0; r < 4; ++r) {
            float m = fmaxf(fmaxf(acc[mi][0][r], acc[mi][1][r]),
                            fmaxf(acc[mi][2][r], acc[mi][3][r]));
            #pragma unroll
            for (int msk = 8; msk >= 1; msk >>= 1) m = fmaxf(m, __shfl_xor(m, msk));
            rmax[mi][r] = m;
            if (l15 == 0) smax[(wm0 + mi * 16 + quad * 4 + r) * 2 + (wave & 1)] = m;
        }
    __syncthreads();
    #pragma unroll
    for (int mi = 0; mi < 2; ++mi)
        #pragma unroll
        for (int r = 0; r < 4; ++r) {
            int row = wm0 + mi * 16 + quad * 4 + r;
            rmax[mi][r] = fmaxf(smax[row * 2], smax[row * 2 + 1]);
        }

    // exp + row sums
    #pragma unroll
    for (int mi = 0; mi < 2; ++mi)
        #pragma unroll
        for (int r = 0; r < 4; ++r) {
            float s = 0.f;
            #pragma unroll
            for (int ni = 0; ni < 4; ++ni) {
                float p = __expf(acc[mi][ni][r] - rmax[mi][r]);
                acc[mi][ni][r] = p;
                s += p;
            }
            #pragma unroll
            for (int msk = 8; msk >= 1; msk >>= 1) s += __shfl_xor(s, msk);
            if (l15 == 0) ssum[(wm0 + mi * 16 + quad * 4 + r) * 2 + (wave & 1)] = s;
        }

    // half 0: even waves (wn0==0) write P~ cols 0..63 into Ps[128][72]
    if ((wave & 1) == 0) {
        #pragma unroll
        for (int mi = 0; mi < 2; ++mi) {
            int row = wm0 + mi * 16 + quad * 4;
            #pragma unroll
            for (int ni = 0; ni < 4; ++ni) {
                int col = ni * 16 + l15;
                #pragma unroll
                for (int r = 0; r < 4; ++r)
                    Ps[(row + r) * 72 + col] =
                        (unsigned short)__bfloat16_as_ushort(__float2bfloat16(acc[mi][ni][r]));
            }
        }
    }
    // write prefetched V chunk: Vs[j][k], xor-swizzled 16B chunks
    #pragma unroll
    for (int p = 0; p < 2; ++p) {
        int j = (tid >> 4) + p * 32;
        int ch = tid & 15;
        *reinterpret_cast<uint4*>(&Vs[j * 136 + ((ch ^ (j & 7)) * 8)]) = vreg[p];
    }
    __syncthreads();

    // per-row stats out (m, l)
    if (tid < 128) {
        float m = fmaxf(smax[tid * 2], smax[tid * 2 + 1]);
        float l = ssum[tid * 2] + ssum[tid * 2 + 1];
        long long o = (((long long)b * 16 + bx) * SS + m0 + tid) * 2;
        stats[o] = m;
        stats[o + 1] = l;
    }

    // O' = P~ . V  in two K-halves (k-chunk order 0,1,2,3 == monolithic version)
    const int wmv = wave * 16;
    floatx4 accO[4] = {};
    __builtin_amdgcn_s_setprio(1);
    #pragma unroll
    for (int sk = 0; sk < 2; ++sk) {                       // half 0: kc = sk
        bf16x8 af = *reinterpret_cast<const bf16x8*>(
            &Ps[(wmv + l15) * 72 + sk * 32 + quad * 8]);
        #pragma unroll
        for (int ni = 0; ni < 4; ++ni) {
            bf16x8 bfv = *reinterpret_cast<const bf16x8*>(
                &Vs[(ni * 16 + l15) * 136 + (((sk << 2) | quad) ^ sw7) * 8]);
            accO[ni] = __builtin_amdgcn_mfma_f32_16x16x32_bf16(af, bfv, accO[ni], 0, 0, 0);
        }
    }
    __builtin_amdgcn_s_setprio(0);
    __syncthreads();

    // half 1: odd waves (wn0==64) write P~ cols 64..127
    if ((wave & 1) == 1) {
        #pragma unroll
        for (int mi = 0; mi < 2; ++mi) {
            int row = wm0 + mi * 16 + quad * 4;
            #pragma unroll
            for (int ni = 0; ni < 4; ++ni) {
                int col = ni * 16 + l15;
                #pragma unroll
                for (int r = 0; r < 4; ++r)
                    Ps[(row + r) * 72 + col] =
                        (unsigned short)__bfloat16_as_ushort(__float2bfloat16(acc[mi][ni][r]));
            }
        }
    }
    __syncthreads();

    __builtin_amdgcn_s_setprio(1);
    #pragma unroll
    for (int sk = 0; sk < 2; ++sk) {                       // half 1: kc = 2 + sk
        const int kc = 2 + sk;
        bf16x8 af = *reinterpret_cast<const bf16x8*>(
            &Ps[(wmv + l15) * 72 + sk * 32 + quad * 8]);
        #pragma unroll
        for (int ni = 0; ni < 4; ++ni) {
            bf16x8 bfv = *reinterpret_cast<const bf16x8*>(
                &Vs[(ni * 16 + l15) * 136 + (((kc << 2) | quad) ^ sw7) * 8]);
            accO[ni] = __builtin_amdgcn_mfma_f32_16x16x32_bf16(af, bfv, accO[ni], 0, 0, 0);
        }
    }
    __builtin_amdgcn_s_setprio(0);

    #pragma unroll
    for (int ni = 0; ni < 4; ++ni)
        #pragma unroll
        for (int r = 0; r < 4; ++r)
            part[(((long long)b * 16 + bx) * SS + m0 + wmv + quad * 4 + r) * 64 + ni * 16 + l15]
                = __float2bfloat16(accO[ni][r]);
}

// ---------------- combine k-tile partials (vectorized x8 bf16 loads) ----------------
__global__ __launch_bounds__(256) void combine(const bf16* __restrict__ part,
                                               const float* __restrict__ stats,
                                               float* __restrict__ out) {
    int tid = blockIdx.x * 256 + threadIdx.x;   // over 8192*8
    int row = tid >> 3;
    int col8 = (tid & 7) * 8;
    int b = row >> 11, s = row & (SS - 1);
    int nt = (s >> 7) + 1;                      // live k-tiles for this row

    float m[16], l[16], M = -INFINITY;
    #pragma unroll
    for (int t = 0; t < 16; ++t)
        if (t < nt) {
            long long o = (((long long)b * 16 + t) * SS + s) * 2;
            m[t] = stats[o];
            l[t] = stats[o + 1];
            M = fmaxf(M, m[t]);
        }
    float O[8] = {};
    float L = 0.f;
    #pragma unroll
    for (int t = 0; t < 16; ++t)
        if (t < nt) {
            float wgt = __expf(m[t] - M);
            L += wgt * l[t];
            union { uint4 q; unsigned short u[8]; } ld;
            ld.q = *reinterpret_cast<const uint4*>(
                part + (((long long)b * 16 + t) * SS + s) * 64 + col8);
            #pragma unroll
            for (int j = 0; j < 8; ++j)
                O[j] += wgt * __uint_as_float((unsigned)ld.u[j] << 16);
        }
    float rinv = 1.0f / L;
    float4 o0 = {O[0] * rinv, O[1] * rinv, O[2] * rinv, O[3] * rinv};
    float4 o1 = {O[4] * rinv, O[5] * rinv, O[6] * rinv, O[7] * rinv};
    float4* dst = reinterpret_cast<float4*>(out + (long long)row * 64 + col8);
    dst[0] = o0;
    dst[1] = o1;
}

extern "C" void kernel_launch(void* const* d_in, const int* in_sizes, int n_in,
                              void* d_out, int out_size, void* d_ws, size_t ws_size,
                              hipStream_t stream) {
    const float* x  = (const float*)d_in[0];
    const float* Wq = (const float*)d_in[1];
    const float* Wk = (const float*)d_in[2];
    const float* Wv = (const float*)d_in[3];
    float* out = (float*)d_out;

    char* w = (char*)d_ws;
    bf16* xb   = (bf16*)(w + XB_OFF);
    bf16* wqb  = (bf16*)(w + WQB_OFF);
    bf16* wkb  = (bf16*)(w + WKB_OFF);
    bf16* wt2  = (bf16*)(w + WT2_OFF);
    float* mtp = (float*)(w + MTP_OFF);
    bf16* yv   = (bf16*)(w + YV_OFF);
    bf16* vt   = (bf16*)(w + VT_OFF);
    bf16* part = (bf16*)(w + PRT_OFF);
    float* stats = (float*)(w + STA_OFF);

    // 1. fused prep: x->xb, Wq/Wk->bf16, Wv->wt2 rows 512..575 (transposed)
    prep<<<6176, 256, 0, stream>>>(x, Wq, Wk, Wv, xb, wqb, wkb, wt2);

    // 2. Mt = Wk·Wq^T [512x512] (split-K 8 partials + reduce) -> wt2 rows 0..511
    gemm_mt<<<128, 256, 0, stream>>>(wkb, wqb, mtp);
    reduce_mt<<<65536 / 256, 256, 0, stream>>>((const float4*)mtp, wt2);

    // 3. yv = xb·wt2^T (y cols) + vt written transposed directly from the v N-tile
    gemm_proj<<<320, 256, 0, stream>>>(xb, wt2, yv, vt);

    // 4. fused attention tiles: scores = y·x^T (K=512), softmax, P~V
    attn_fused<<<dim3(136, 1, BB), 512, 0, stream>>>(yv, xb, vt, part, stats);

    // 5. combine partials -> out
    combine<<<ROWS * 8 / 256, 256, 0, stream>>>(part, stats, out);
}